// Round 1
// 91.826 us; speedup vs baseline: 1.0345x; 1.0345x over previous
//
#include <hip/hip_runtime.h>

#define IMG 8
#define LH 150
#define LQ 10
#define KITER 10   // 9 scan steps + final conv
#define ROW (IMG * IMG + 2)   // 66 floats per batch row

// Packed fp32 pair: item0 in .x, item1 in .y -> v_pk_fma_f32 (full-rate on CDNA).
typedef float f32x2 __attribute__((ext_vector_type(2)));

// ds_bpermute with precomputed BYTE address. Full-wave convergence required.
__device__ __forceinline__ float bperm(int byte_addr, float v) {
    return __builtin_bit_cast(float,
        __builtin_amdgcn_ds_bpermute(byte_addr, __builtin_bit_cast(int, v)));
}

// DPP lane shift within 16-lane rows. 0x111 = row_shr:1 (lane i <- i-1),
// 0x101 = row_shl:1 (lane i <- i+1). Invalid/bound lanes -> 0.0 (bound_ctrl),
// cross-grid-row lanes (x==0 / x==7) produce garbage that hits a 0.0 weight.
template <int CTRL>
__device__ __forceinline__ float dppf(float v) {
    return __builtin_bit_cast(float,
        __builtin_amdgcn_update_dpp(0, __builtin_bit_cast(int, v),
                                    CTRL, 0xF, 0xF, true));
}
#define DPP_SHR1 0x111
#define DPP_SHL1 0x101

__device__ __forceinline__ f32x2 fma2(f32x2 a, f32x2 b, f32x2 c) {
#if __has_builtin(__builtin_elementwise_fma)
    return __builtin_elementwise_fma(a, b, c);
#else
    return a * b + c;   // contracts to v_pk_fma_f32 under default fp-contract
#endif
}
__device__ __forceinline__ f32x2 max2(f32x2 a, f32x2 b) {
    f32x2 r; r.x = fmaxf(a.x, b.x); r.y = fmaxf(a.y, b.y); return r;
}

// 3x3 neighbor gather for a packed pair: 4 ds_bpermute (vertical, lane+-8)
// + 12 DPP movs (horizontal, lane+-1) + center free. Replaces 18 bpermutes.
__device__ __forceinline__ void gather9(f32x2 vn[9], f32x2 v, int aU, int aD) {
    f32x2 vU, vD;
    vU.x = bperm(aU, v.x); vU.y = bperm(aU, v.y);
    vD.x = bperm(aD, v.x); vD.y = bperm(aD, v.y);
    vn[1] = vU; vn[4] = v; vn[7] = vD;
    vn[0].x = dppf<DPP_SHR1>(vU.x); vn[0].y = dppf<DPP_SHR1>(vU.y);
    vn[2].x = dppf<DPP_SHL1>(vU.x); vn[2].y = dppf<DPP_SHL1>(vU.y);
    vn[3].x = dppf<DPP_SHR1>(v.x);  vn[3].y = dppf<DPP_SHR1>(v.y);
    vn[5].x = dppf<DPP_SHL1>(v.x);  vn[5].y = dppf<DPP_SHL1>(v.y);
    vn[6].x = dppf<DPP_SHR1>(vD.x); vn[6].y = dppf<DPP_SHR1>(vD.y);
    vn[8].x = dppf<DPP_SHL1>(vD.x); vn[8].y = dppf<DPP_SHL1>(vD.y);
}

// ---------------------------------------------------------------------------
// Pre-kernel: collapse h/r convs (exact — no nonlinearity between h and r).
// ---------------------------------------------------------------------------
__global__ void weff_kernel(const float* __restrict__ Wh,
                            const float* __restrict__ bh,
                            const float* __restrict__ Wr,
                            float* __restrict__ ws) {
    const int wv = threadIdx.x >> 6;   // 0..9 (wave-uniform)
    const int lane = threadIdx.x & 63;
    float partial = 0.f;
    for (int c = lane; c < LH; c += 64) {
        const float wr = Wr[c];
        partial += wr * ((wv < 9) ? Wh[c * 9 + wv] : bh[c]);
    }
    #pragma unroll
    for (int off = 32; off > 0; off >>= 1)
        partial += __shfl_xor(partial, off);   // full wave active
    if (lane == 0) ws[wv] = partial;
}

// ---------------------------------------------------------------------------
// Main kernel: one wave = TWO batch items packed into f32x2 lanes; lane=pixel.
// Round-8 changes vs previous best:
//  (a) item-pair packing -> v_pk_fma_f32 halves the dominant fma stream
//      (180 -> 90 per step per wave); weights pre-masked AND duplicated into
//      both pk halves (wp[o][t] = {w*m, w*m}), VGPR-resident -> k-loop still
//      has no s_loads.
//  (b) horizontal taps via DPP row_shr:1/row_shl:1 (VALU) instead of
//      ds_bpermute; only vertical lane+-8 stays on the DS pipe; center tap
//      needs no shuffle. 18 -> 4 ds ops per step per wave.
// Tap order, max trees, and mask folding are bit-identical to the previous
// verified kernel.
// ---------------------------------------------------------------------------
__global__ __launch_bounds__(256, 2) void vin_kernel(
    const float* __restrict__ S,
    const float* __restrict__ Wq,
    const float* __restrict__ w,
    const float* __restrict__ Wfc,
    const float* __restrict__ ws,
    float* __restrict__ out,
    int B) {
    const int wave = threadIdx.x >> 6;
    const int lane = threadIdx.x & 63;
    const long b0 = (long)(blockIdx.x * 4 + wave) * 2;   // items b0, b0+1
    if (b0 >= B) return;                                  // wave-uniform

    const int y = lane >> 3, x = lane & 7;

    // Zero-pad masks for the 9 taps; vertical-neighbor byte addresses.
    float msk[9];
    #pragma unroll
    for (int t = 0; t < 9; ++t) {
        const int ny = y + t / 3 - 1, nx = x + t % 3 - 1;
        msk[t] = (((unsigned)ny < 8u) && ((unsigned)nx < 8u)) ? 1.f : 0.f;
    }
    const int aU = ((y > 0) ? (lane - 8) : 0) << 2;
    const int aD = ((y < 7) ? (lane + 8) : 0) << 2;

    const float* S0 = S + b0 * ROW;
    f32x2 X; X.x = S0[lane]; X.y = S0[ROW + lane];
    const int sel0 = ((int)S0[IMG * IMG] * 8 + (int)S0[IMG * IMG + 1]) << 2;
    const int sel1 = ((int)S0[ROW + IMG * IMG] * 8 + (int)S0[ROW + IMG * IMG + 1]) << 2;

    // r = conv(X, Weff, pad=1) + beff   (packed pair)
    f32x2 r;
    {
        f32x2 xn[9]; gather9(xn, X, aU, aD);
        const float b = ws[9];
        r.x = b; r.y = b;
        #pragma unroll
        for (int t = 0; t < 9; ++t) {
            const float wm = ws[t] * msk[t];
            f32x2 w2; w2.x = wm; w2.y = wm;
            r = fma2(xn[t], w2, r);
        }
    }

    // qr[o] = conv(r, Wq, pad=1) — loop-invariant across the value iteration.
    f32x2 qr[LQ];
    {
        f32x2 rn[9]; gather9(rn, r, aU, aD);
        #pragma unroll
        for (int t = 0; t < 9; ++t) {
            f32x2 a; a.x = rn[t].x * msk[t]; a.y = rn[t].y * msk[t];
            #pragma unroll
            for (int o = 0; o < LQ; ++o) {
                const float wq = Wq[o * 9 + t];      // wave-uniform (SGPR)
                f32x2 w2; w2.x = wq; w2.y = wq;
                qr[o] = (t == 0) ? (a * w2) : fma2(a, w2, qr[o]);
            }
        }
    }

    // Per-lane masked scan-conv weights, duplicated into both pk halves.
    f32x2 wp[LQ][9];
    #pragma unroll
    for (int o = 0; o < LQ; ++o)
        #pragma unroll
        for (int t = 0; t < 9; ++t) {
            const float wm = w[o * 9 + t] * msk[t];  // exact (x1 or x0)
            wp[o][t].x = wm; wp[o][t].y = wm;
        }

    // v = max over channels of qr (same tree as previous kernel's max10)
    f32x2 v;
    {
        const f32x2 g0 = max2(max2(qr[0], qr[1]), qr[2]);
        const f32x2 g1 = max2(max2(qr[3], qr[4]), qr[5]);
        const f32x2 g2 = max2(max2(qr[6], qr[7]), qr[8]);
        v = max2(max2(g0, g1), max2(g2, qr[9]));
    }

    // 9 scan steps: gather (4 bperm + 12 dpp) -> 90 pk_fma -> packed max.
    #pragma unroll
    for (int k = 0; k < KITER - 1; ++k) {
        f32x2 vn[9]; gather9(vn, v, aU, aD);
        f32x2 m;
        #pragma unroll
        for (int o = 0; o < LQ; ++o) {
            f32x2 acc = qr[o];
            #pragma unroll
            for (int t = 0; t < 9; ++t)
                acc = fma2(vn[t], wp[o][t], acc);
            m = (o == 0) ? acc : max2(m, acc);
        }
        v = m;
    }

    // Final conv fused with sel-lane broadcast and the Wfc dot (streamed:
    // no qs[] array — keeps peak VGPR down).
    float oacc = 0.f;
    {
        f32x2 vn[9]; gather9(vn, v, aU, aD);
        const int row = lane & 7;
        #pragma unroll
        for (int o = 0; o < LQ; ++o) {
            f32x2 acc = qr[o];
            #pragma unroll
            for (int t = 0; t < 9; ++t)
                acc = fma2(vn[t], wp[o][t], acc);
            const float q0 = bperm(sel0, acc.x);     // full convergence
            const float q1 = bperm(sel1, acc.y);
            oacc = fmaf((lane < 8) ? q0 : q1, Wfc[row * LQ + o], oacc);
        }
    }
    // Lanes 0..7 emit item b0's logits, lanes 8..15 item b0+1's.
    if (lane < 16) out[b0 * 8 + lane] = oacc;
}

extern "C" void kernel_launch(void* const* d_in, const int* in_sizes, int n_in,
                              void* d_out, int out_size, void* d_ws, size_t ws_size,
                              hipStream_t stream) {
    const float* S   = (const float*)d_in[0];
    const float* Wh  = (const float*)d_in[1];
    const float* bh  = (const float*)d_in[2];
    const float* Wr  = (const float*)d_in[3];
    const float* Wq  = (const float*)d_in[4];
    const float* w   = (const float*)d_in[5];
    const float* Wfc = (const float*)d_in[6];
    float* out = (float*)d_out;
    float* ws  = (float*)d_ws;

    const int B = in_sizes[0] / ROW;

    weff_kernel<<<1, 640, 0, stream>>>(Wh, bh, Wr, ws);

    // 4 waves/block, 2 items/wave => 8 items per block.
    const int grid = (B + 7) / 8;
    vin_kernel<<<grid, 256, 0, stream>>>(S, Wq, w, Wfc, ws, out, B);
}